// Round 4
// baseline (333.769 us; speedup 1.0000x reference)
//
#include <hip/hip_runtime.h>
#include <hip/hip_bf16.h>

#define A_N   2048
#define D_N   64
#define FL_N  12
#define KTOT  (A_N * FL_N)          // 24576
#define S_SPLIT 64
#define KCHUNK (KTOT / S_SPLIT)     // 384
#define NSTEP (KCHUNK / 32)         // 12

typedef __attribute__((ext_vector_type(8))) short bf16x8;  // 8 bf16 = 4 VGPRs
typedef __attribute__((ext_vector_type(4))) short bf16x4;  // 8 B
typedef __attribute__((ext_vector_type(4))) float f32x4;

__device__ __forceinline__ short f2bf(float f) {
  union { __hip_bfloat16 b; short s; } u;
  u.b = __float2bfloat16(f);
  return u.s;
}

// ---------- fused setup + conn conversion ----------
// blocks [0,192):   P2_i[o][f][d] = pf_i[o,f,d]*bf_i[o,f,0]
// blocks [192,704): bond_i[a][o]  = sum_f bp[a,f,0]*bf_i[o,f,1]+bp[a,f,1]*bf_i[o,f,2]
// blocks [704,768): xb = bf16(x)
// blocks [768,4864): connb = bf16(conn), grid-stride 6 chunks x 8 floats/thread
__global__ void k_setup_cvt(const float* __restrict__ pf0, const float* __restrict__ bf0,
                            const float* __restrict__ pf1, const float* __restrict__ bf1,
                            const float* __restrict__ bp, const float* __restrict__ x,
                            const float* __restrict__ conn,
                            short* __restrict__ P2_0, short* __restrict__ P2_1,
                            float* __restrict__ bond0, float* __restrict__ bond1,
                            short* __restrict__ xb, short* __restrict__ connb) {
  int b = blockIdx.x, t = threadIdx.x;
  if (b >= 768) {
    size_t slot = (size_t)(b - 768) * 256 + t;        // < 1048576
#pragma unroll
    for (int c = 0; c < 6; ++c) {
      size_t i = (slot + (size_t)c * 1048576) * 8;    // covers 50331648 floats exactly
      f32x4 a0 = __builtin_nontemporal_load((const f32x4*)(conn + i));
      f32x4 a1 = __builtin_nontemporal_load((const f32x4*)(conn + i + 4));
      bf16x8 v;
      v[0]=f2bf(a0[0]); v[1]=f2bf(a0[1]); v[2]=f2bf(a0[2]); v[3]=f2bf(a0[3]);
      v[4]=f2bf(a1[0]); v[5]=f2bf(a1[1]); v[6]=f2bf(a1[2]); v[7]=f2bf(a1[3]);
      *(bf16x8*)(connb + i) = v;
    }
    return;
  }
  if (b < 192) {
    int idx = b * 256 + t;                       // < 49152
    int f = (idx >> 6) % FL_N;
    int o = idx / (D_N * FL_N);
    P2_0[idx] = f2bf(pf0[idx] * bf0[(o * FL_N + f) * 3]);
    P2_1[idx] = f2bf(pf1[idx] * bf1[(o * FL_N + f) * 3]);
  } else if (b < 704) {
    int o = t & 63;
    int a = (b - 192) * 4 + (t >> 6);
    float s0 = 0.f, s1 = 0.f;
#pragma unroll
    for (int f = 0; f < FL_N; ++f) {
      float c0 = bp[(a * FL_N + f) * 2 + 0];
      float c1 = bp[(a * FL_N + f) * 2 + 1];
      s0 += c0 * bf0[(o * FL_N + f) * 3 + 1] + c1 * bf0[(o * FL_N + f) * 3 + 2];
      s1 += c0 * bf1[(o * FL_N + f) * 3 + 1] + c1 * bf1[(o * FL_N + f) * 3 + 2];
    }
    bond0[a * D_N + o] = s0;
    bond1[a * D_N + o] = s1;
  } else {
    int i = ((b - 704) * 256 + t) * 8;
    f32x4 a0 = *(const f32x4*)(x + i);
    f32x4 a1 = *(const f32x4*)(x + i + 4);
    bf16x8 v;
    v[0]=f2bf(a0[0]); v[1]=f2bf(a0[1]); v[2]=f2bf(a0[2]); v[3]=f2bf(a0[3]);
    v[4]=f2bf(a1[0]); v[5]=f2bf(a1[1]); v[6]=f2bf(a1[2]); v[7]=f2bf(a1[3]);
    *(bf16x8*)(xb + i) = v;
  }
}

// ---------- Bt prep (shared MFMA body) ----------
// Bt[o][k*FL+f] = sum_d h[k,d] * P2[o,f,d];  16x16x32: M=o(16/wave), N=k(16/block), K=d(64)
__device__ __forceinline__ void prep_body(bf16x8 h0, bf16x8 h1,
                                          const short* __restrict__ P2,
                                          short* __restrict__ Bt,
                                          int k0, int lane, int w) {
  int l15 = lane & 15, grp = lane >> 4;
  const short* prow = P2 + (w * 16 + l15) * (FL_N * D_N) + grp * 8;
  f32x4 acc[FL_N];
#pragma unroll
  for (int f = 0; f < FL_N; ++f) {
    bf16x8 p0 = *(const bf16x8*)(prow + f * D_N);
    bf16x8 p1 = *(const bf16x8*)(prow + f * D_N + 32);
    f32x4 c = {0.f, 0.f, 0.f, 0.f};
    c = __builtin_amdgcn_mfma_f32_16x16x32_bf16(p0, h0, c, 0, 0, 0);
    c = __builtin_amdgcn_mfma_f32_16x16x32_bf16(p1, h1, c, 0, 0, 0);
    acc[f] = c;
  }
  // D layout: row(o) = grp*4 + r (+w*16), col(k) = l15 (+k0)
#pragma unroll
  for (int r = 0; r < 4; ++r) {
    int o = w * 16 + grp * 4 + r;
    int k = k0 + l15;
    short ov[FL_N];
#pragma unroll
    for (int f = 0; f < FL_N; ++f) ov[f] = f2bf(acc[f][r]);
    short* dst = Bt + (size_t)o * KTOT + (size_t)k * FL_N;
    *(bf16x4*)(dst)     = *(const bf16x4*)(ov);
    *(bf16x4*)(dst + 4) = *(const bf16x4*)(ov + 4);
    *(bf16x4*)(dst + 8) = *(const bf16x4*)(ov + 8);
  }
}

// prep for conv0: h = xb
__global__ void k_prep0(const short* __restrict__ xb, const short* __restrict__ P2,
                        short* __restrict__ Bt) {
  int lane = threadIdx.x & 63, w = threadIdx.x >> 6;
  int l15 = lane & 15, grp = lane >> 4;
  int k0 = blockIdx.x * 16;
  const short* hrow = xb + (k0 + l15) * D_N + grp * 8;
  bf16x8 h0 = *(const bf16x8*)(hrow);
  bf16x8 h1 = *(const bf16x8*)(hrow + 32);
  prep_body(h0, h1, P2, Bt, k0, lane, w);
}

// prep for conv c>0: reduce prev conv's partials for this block's 16 rows,
// apply bond (+x) + relu, stage h tile in LDS, then MFMA-prep Bt.
template <int ADDX>
__global__ void k_prep_r(const float* __restrict__ part, const float* __restrict__ bond,
                         const float* __restrict__ x, const short* __restrict__ P2,
                         short* __restrict__ Bt) {
  __shared__ short hsh[16 * 64];
  int t = threadIdx.x;
  int k0 = blockIdx.x * 16;
  int r  = t >> 4;            // 0..15 local row
  int d0 = (t & 15) * 4;      // 4 floats per thread
  size_t base = (size_t)(k0 + r) * D_N + d0;
  f32x4 s = *(const f32x4*)(bond + base);
#pragma unroll 16
  for (int si = 0; si < S_SPLIT; ++si) {
    f32x4 p = *(const f32x4*)(part + (size_t)si * (A_N * D_N) + base);
    s[0] += p[0]; s[1] += p[1]; s[2] += p[2]; s[3] += p[3];
  }
  if (ADDX) {
    f32x4 xv = *(const f32x4*)(x + base);
    s[0] += xv[0]; s[1] += xv[1]; s[2] += xv[2]; s[3] += xv[3];
  }
  bf16x4 hv;
  hv[0] = f2bf(fmaxf(s[0], 0.f)); hv[1] = f2bf(fmaxf(s[1], 0.f));
  hv[2] = f2bf(fmaxf(s[2], 0.f)); hv[3] = f2bf(fmaxf(s[3], 0.f));
  *(bf16x4*)(&hsh[r * 64 + d0]) = hv;
  __syncthreads();
  int lane = t & 63, w = t >> 6, l15 = lane & 15, grp = lane >> 4;
  bf16x8 h0 = *(const bf16x8*)(&hsh[l15 * 64 + grp * 8]);
  bf16x8 h1 = *(const bf16x8*)(&hsh[l15 * 64 + grp * 8 + 32]);
  prep_body(h0, h1, P2, Bt, k0, lane, w);
}

// ---------- big GEMM: part[kc][a][o] = sum_{j in chunk} connb[a][j] * Bt[o][j] ----------
// grid (32, 64), 256 thr = 4 waves; 32 waves/CU resident (VGPR<=64).
__global__ __launch_bounds__(256, 8) void k_gemm_b16(const short* __restrict__ connb,
                                                     const short* __restrict__ Bt,
                                                     float* __restrict__ part) {
  int mt   = blockIdx.x;
  int kc   = blockIdx.y;
  int lane = threadIdx.x & 63;
  int w    = threadIdx.x >> 6;
  int l15  = lane & 15;
  int grp  = lane >> 4;

  int row = mt * 64 + w * 16 + l15;
  const short* abp = connb + (size_t)row * KTOT + (size_t)kc * KCHUNK + grp * 8;
  const short* bp  = Bt + (size_t)l15 * KTOT + (size_t)kc * KCHUNK + grp * 8;

  f32x4 acc0 = {0,0,0,0}, acc1 = {0,0,0,0}, acc2 = {0,0,0,0}, acc3 = {0,0,0,0};

#pragma unroll
  for (int ks = 0; ks < NSTEP; ++ks) {
    const int o = ks * 32;
    bf16x8 af = *(const bf16x8*)(abp + o);
    bf16x8 b0 = *(const bf16x8*)(bp + o);
    bf16x8 b1 = *(const bf16x8*)(bp + o + (size_t)16 * KTOT);
    bf16x8 b2 = *(const bf16x8*)(bp + o + (size_t)32 * KTOT);
    bf16x8 b3 = *(const bf16x8*)(bp + o + (size_t)48 * KTOT);
    acc0 = __builtin_amdgcn_mfma_f32_16x16x32_bf16(af, b0, acc0, 0, 0, 0);
    acc1 = __builtin_amdgcn_mfma_f32_16x16x32_bf16(af, b1, acc1, 0, 0, 0);
    acc2 = __builtin_amdgcn_mfma_f32_16x16x32_bf16(af, b2, acc2, 0, 0, 0);
    acc3 = __builtin_amdgcn_mfma_f32_16x16x32_bf16(af, b3, acc3, 0, 0, 0);
  }

  float* p = part + (size_t)kc * (A_N * D_N);
  int ab = mt * 64 + w * 16 + grp * 4;
#pragma unroll
  for (int r = 0; r < 4; ++r) {
    float* pr = p + (size_t)(ab + r) * D_N + l15;
    pr[0]  = acc0[r];
    pr[16] = acc1[r];
    pr[32] = acc2[r];
    pr[48] = acc3[r];
  }
}

// ---------- final reduce -> f32 out (512 blocks, 1 elem/thread) ----------
__global__ void k_final(const float* __restrict__ part, const float* __restrict__ bond,
                        const float* __restrict__ x, float* __restrict__ out) {
  int i = blockIdx.x * 256 + threadIdx.x;   // 131072 total
  float s = bond[i];
#pragma unroll 16
  for (int si = 0; si < S_SPLIT; ++si) s += part[(size_t)si * (A_N * D_N) + i];
  out[i] = fmaxf(s + x[i], 0.f);
}

// ---------- launch ----------
extern "C" void kernel_launch(void* const* d_in, const int* in_sizes, int n_in,
                              void* d_out, int out_size, void* d_ws, size_t ws_size,
                              hipStream_t stream) {
  const float* x    = (const float*)d_in[0];
  const float* conn = (const float*)d_in[1];
  const float* bprp = (const float*)d_in[2];
  const float* pf0  = (const float*)d_in[3];
  const float* bf0  = (const float*)d_in[4];
  const float* pf1  = (const float*)d_in[5];
  const float* bf1  = (const float*)d_in[6];
  float* out = (float*)d_out;

  char* ws = (char*)d_ws;
  size_t off = 0;
  short* connb = (short*)(ws + off); off += (size_t)A_N * KTOT * 2;           // 100.7 MB
  short* Bt    = (short*)(ws + off); off += (size_t)D_N * KTOT * 2;           // 3 MB
  float* part  = (float*)(ws + off); off += (size_t)S_SPLIT * A_N * D_N * 4;  // 33.6 MB
  short* xb    = (short*)(ws + off); off += (size_t)A_N * D_N * 2;
  float* bond0 = (float*)(ws + off); off += (size_t)A_N * D_N * 4;
  float* bond1 = (float*)(ws + off); off += (size_t)A_N * D_N * 4;
  short* P2_0  = (short*)(ws + off); off += (size_t)D_N * FL_N * D_N * 2;
  short* P2_1  = (short*)(ws + off); off += (size_t)D_N * FL_N * D_N * 2;

  k_setup_cvt<<<4864, 256, 0, stream>>>(pf0, bf0, pf1, bf1, bprp, x, conn,
                                        P2_0, P2_1, bond0, bond1, xb, connb);

  dim3 ggrid(32, S_SPLIT);

  // conv0: h = x
  k_prep0<<<128, 256, 0, stream>>>(xb, P2_0, Bt);
  k_gemm_b16<<<ggrid, 256, 0, stream>>>(connb, Bt, part);

  // conv1: h1 = relu(conv0); bond0; P2_0
  k_prep_r<0><<<128, 256, 0, stream>>>(part, bond0, x, P2_0, Bt);
  k_gemm_b16<<<ggrid, 256, 0, stream>>>(connb, Bt, part);

  // conv2: h2 = relu(conv1 + x); bond0; P2_1
  k_prep_r<1><<<128, 256, 0, stream>>>(part, bond0, x, P2_1, Bt);
  k_gemm_b16<<<ggrid, 256, 0, stream>>>(connb, Bt, part);

  // conv3: h3 = relu(conv2); bond1; P2_1
  k_prep_r<0><<<128, 256, 0, stream>>>(part, bond1, x, P2_1, Bt);
  k_gemm_b16<<<ggrid, 256, 0, stream>>>(connb, Bt, part);

  // out = relu(conv3 + x)
  k_final<<<512, 256, 0, stream>>>(part, bond1, x, out);
}

// Round 5
// 315.117 us; speedup vs baseline: 1.0592x; 1.0592x over previous
//
#include <hip/hip_runtime.h>
#include <hip/hip_bf16.h>

#define A_N   2048
#define D_N   64
#define FL_N  12
#define KTOT  (A_N * FL_N)          // 24576
#define S_SPLIT 16
#define KCHUNK (KTOT / S_SPLIT)     // 1536 cols per kc-chunk
#define WSUB  (KCHUNK / 4)          // 384 cols per wave
#define NSTEP (WSUB / 32)           // 12 k-steps per wave

typedef __attribute__((ext_vector_type(8))) short bf16x8;  // 8 bf16 = 4 VGPRs
typedef __attribute__((ext_vector_type(4))) short bf16x4;  // 8 B
typedef __attribute__((ext_vector_type(4))) float f32x4;

__device__ __forceinline__ short f2bf(float f) {
  union { __hip_bfloat16 b; short s; } u;
  u.b = __float2bfloat16(f);
  return u.s;
}

// ---------- fused setup + conn conversion ----------
// blocks [0,192):   P2_i[o][f][d] = pf_i[o,f,d]*bf_i[o,f,0]
// blocks [192,704): bond_i[a][o]  = sum_f bp[a,f,0]*bf_i[o,f,1]+bp[a,f,1]*bf_i[o,f,2]
// blocks [704,768): xb = bf16(x)
// blocks [768,4864): connb = bf16(conn), 6 chunks x 8 floats/thread (NT reads:
//   keep conn OUT of L3 so connb/part/Bt stay resident)
__global__ void k_setup_cvt(const float* __restrict__ pf0, const float* __restrict__ bf0,
                            const float* __restrict__ pf1, const float* __restrict__ bf1,
                            const float* __restrict__ bp, const float* __restrict__ x,
                            const float* __restrict__ conn,
                            short* __restrict__ P2_0, short* __restrict__ P2_1,
                            float* __restrict__ bond0, float* __restrict__ bond1,
                            short* __restrict__ xb, short* __restrict__ connb) {
  int b = blockIdx.x, t = threadIdx.x;
  if (b >= 768) {
    size_t slot = (size_t)(b - 768) * 256 + t;        // < 1048576
#pragma unroll
    for (int c = 0; c < 6; ++c) {
      size_t i = (slot + (size_t)c * 1048576) * 8;    // covers 50331648 floats exactly
      f32x4 a0 = __builtin_nontemporal_load((const f32x4*)(conn + i));
      f32x4 a1 = __builtin_nontemporal_load((const f32x4*)(conn + i + 4));
      bf16x8 v;
      v[0]=f2bf(a0[0]); v[1]=f2bf(a0[1]); v[2]=f2bf(a0[2]); v[3]=f2bf(a0[3]);
      v[4]=f2bf(a1[0]); v[5]=f2bf(a1[1]); v[6]=f2bf(a1[2]); v[7]=f2bf(a1[3]);
      *(bf16x8*)(connb + i) = v;
    }
    return;
  }
  if (b < 192) {
    int idx = b * 256 + t;                       // < 49152
    int f = (idx >> 6) % FL_N;
    int o = idx / (D_N * FL_N);
    P2_0[idx] = f2bf(pf0[idx] * bf0[(o * FL_N + f) * 3]);
    P2_1[idx] = f2bf(pf1[idx] * bf1[(o * FL_N + f) * 3]);
  } else if (b < 704) {
    int o = t & 63;
    int a = (b - 192) * 4 + (t >> 6);
    float s0 = 0.f, s1 = 0.f;
#pragma unroll
    for (int f = 0; f < FL_N; ++f) {
      float c0 = bp[(a * FL_N + f) * 2 + 0];
      float c1 = bp[(a * FL_N + f) * 2 + 1];
      s0 += c0 * bf0[(o * FL_N + f) * 3 + 1] + c1 * bf0[(o * FL_N + f) * 3 + 2];
      s1 += c0 * bf1[(o * FL_N + f) * 3 + 1] + c1 * bf1[(o * FL_N + f) * 3 + 2];
    }
    bond0[a * D_N + o] = s0;
    bond1[a * D_N + o] = s1;
  } else {
    int i = ((b - 704) * 256 + t) * 8;
    f32x4 a0 = *(const f32x4*)(x + i);
    f32x4 a1 = *(const f32x4*)(x + i + 4);
    bf16x8 v;
    v[0]=f2bf(a0[0]); v[1]=f2bf(a0[1]); v[2]=f2bf(a0[2]); v[3]=f2bf(a0[3]);
    v[4]=f2bf(a1[0]); v[5]=f2bf(a1[1]); v[6]=f2bf(a1[2]); v[7]=f2bf(a1[3]);
    *(bf16x8*)(xb + i) = v;
  }
}

// ---------- Bt prep (shared MFMA body) ----------
// Bt[o][k*FL+f] = sum_d h[k,d] * P2[o,f,d];  16x16x32: M=o(16/wave), N=k(16/block), K=d(64)
__device__ __forceinline__ void prep_body(bf16x8 h0, bf16x8 h1,
                                          const short* __restrict__ P2,
                                          short* __restrict__ Bt,
                                          int k0, int lane, int w) {
  int l15 = lane & 15, grp = lane >> 4;
  const short* prow = P2 + (w * 16 + l15) * (FL_N * D_N) + grp * 8;
  f32x4 acc[FL_N];
#pragma unroll
  for (int f = 0; f < FL_N; ++f) {
    bf16x8 p0 = *(const bf16x8*)(prow + f * D_N);
    bf16x8 p1 = *(const bf16x8*)(prow + f * D_N + 32);
    f32x4 c = {0.f, 0.f, 0.f, 0.f};
    c = __builtin_amdgcn_mfma_f32_16x16x32_bf16(p0, h0, c, 0, 0, 0);
    c = __builtin_amdgcn_mfma_f32_16x16x32_bf16(p1, h1, c, 0, 0, 0);
    acc[f] = c;
  }
  // D layout: row(o) = grp*4 + r (+w*16), col(k) = l15 (+k0)
#pragma unroll
  for (int r = 0; r < 4; ++r) {
    int o = w * 16 + grp * 4 + r;
    int k = k0 + l15;
    short ov[FL_N];
#pragma unroll
    for (int f = 0; f < FL_N; ++f) ov[f] = f2bf(acc[f][r]);
    short* dst = Bt + (size_t)o * KTOT + (size_t)k * FL_N;
    *(bf16x4*)(dst)     = *(const bf16x4*)(ov);
    *(bf16x4*)(dst + 4) = *(const bf16x4*)(ov + 4);
    *(bf16x4*)(dst + 8) = *(const bf16x4*)(ov + 8);
  }
}

// prep for conv0: h = xb
__global__ void k_prep0(const short* __restrict__ xb, const short* __restrict__ P2,
                        short* __restrict__ Bt) {
  int lane = threadIdx.x & 63, w = threadIdx.x >> 6;
  int l15 = lane & 15, grp = lane >> 4;
  int k0 = blockIdx.x * 16;
  const short* hrow = xb + (k0 + l15) * D_N + grp * 8;
  bf16x8 h0 = *(const bf16x8*)(hrow);
  bf16x8 h1 = *(const bf16x8*)(hrow + 32);
  prep_body(h0, h1, P2, Bt, k0, lane, w);
}

// prep for conv c>0: reduce prev conv's partials for this block's 16 rows,
// apply bond (+x) + relu, stage h tile in LDS, then MFMA-prep Bt.
template <int ADDX>
__global__ void k_prep_r(const float* __restrict__ part, const float* __restrict__ bond,
                         const float* __restrict__ x, const short* __restrict__ P2,
                         short* __restrict__ Bt) {
  __shared__ short hsh[16 * 64];
  int t = threadIdx.x;
  int k0 = blockIdx.x * 16;
  int r  = t >> 4;            // 0..15 local row
  int d0 = (t & 15) * 4;      // 4 floats per thread
  size_t base = (size_t)(k0 + r) * D_N + d0;
  f32x4 s = *(const f32x4*)(bond + base);
#pragma unroll
  for (int si = 0; si < S_SPLIT; ++si) {
    f32x4 p = *(const f32x4*)(part + (size_t)si * (A_N * D_N) + base);
    s[0] += p[0]; s[1] += p[1]; s[2] += p[2]; s[3] += p[3];
  }
  if (ADDX) {
    f32x4 xv = *(const f32x4*)(x + base);
    s[0] += xv[0]; s[1] += xv[1]; s[2] += xv[2]; s[3] += xv[3];
  }
  bf16x4 hv;
  hv[0] = f2bf(fmaxf(s[0], 0.f)); hv[1] = f2bf(fmaxf(s[1], 0.f));
  hv[2] = f2bf(fmaxf(s[2], 0.f)); hv[3] = f2bf(fmaxf(s[3], 0.f));
  *(bf16x4*)(&hsh[r * 64 + d0]) = hv;
  __syncthreads();
  int lane = t & 63, w = t >> 6, l15 = lane & 15, grp = lane >> 4;
  bf16x8 h0 = *(const bf16x8*)(&hsh[l15 * 64 + grp * 8]);
  bf16x8 h1 = *(const bf16x8*)(&hsh[l15 * 64 + grp * 8 + 32]);
  prep_body(h0, h1, P2, Bt, k0, lane, w);
}

// ---------- big GEMM ----------
// part[kc][a][o] = sum_{j in chunk kc} connb[a][j] * Bt[o][j]
// Block = 16 rows x KCHUNK(1536) cols; 4 waves each take a 384-col sub-chunk;
// LDS reduce across waves. grid (128 row-tiles, 16 kc) = 2048 blocks, 8/CU.
template <int C>
__global__ __launch_bounds__(256, 8) void k_gemm(const short* __restrict__ connb,
                                                 const short* __restrict__ Bt,
                                                 float* __restrict__ part) {
  __shared__ float red[4][16][64];   // 16 KB
  int t    = threadIdx.x;
  int lane = t & 63;
  int w    = t >> 6;
  int l15  = lane & 15;
  int grp  = lane >> 4;
  int rt   = blockIdx.x;    // row-tile (16 rows)
  int kc   = blockIdx.y;

  const short* abp = connb + (size_t)(rt * 16 + l15) * KTOT
                     + (size_t)kc * KCHUNK + w * WSUB + grp * 8;
  const short* bp  = Bt + (size_t)l15 * KTOT
                     + (size_t)kc * KCHUNK + w * WSUB + grp * 8;

  f32x4 acc0 = {0,0,0,0}, acc1 = {0,0,0,0}, acc2 = {0,0,0,0}, acc3 = {0,0,0,0};

#pragma unroll
  for (int ks = 0; ks < NSTEP; ++ks) {
    const int o = ks * 32;
    bf16x8 af = *(const bf16x8*)(abp + o);
    bf16x8 b0 = *(const bf16x8*)(bp + o);
    bf16x8 b1 = *(const bf16x8*)(bp + o + (size_t)16 * KTOT);
    bf16x8 b2 = *(const bf16x8*)(bp + o + (size_t)32 * KTOT);
    bf16x8 b3 = *(const bf16x8*)(bp + o + (size_t)48 * KTOT);
    acc0 = __builtin_amdgcn_mfma_f32_16x16x32_bf16(af, b0, acc0, 0, 0, 0);
    acc1 = __builtin_amdgcn_mfma_f32_16x16x32_bf16(af, b1, acc1, 0, 0, 0);
    acc2 = __builtin_amdgcn_mfma_f32_16x16x32_bf16(af, b2, acc2, 0, 0, 0);
    acc3 = __builtin_amdgcn_mfma_f32_16x16x32_bf16(af, b3, acc3, 0, 0, 0);
  }

  // D layout: local row = grp*4 + r, col segment j*16 + l15
#pragma unroll
  for (int r = 0; r < 4; ++r) {
    int al = grp * 4 + r;
    red[w][al][l15]      = acc0[r];
    red[w][al][16 + l15] = acc1[r];
    red[w][al][32 + l15] = acc2[r];
    red[w][al][48 + l15] = acc3[r];
  }
  __syncthreads();

  int al = t >> 4;           // 0..15
  int o4 = (t & 15) * 4;     // 0..60
  f32x4 s0 = *(const f32x4*)(&red[0][al][o4]);
  f32x4 s1 = *(const f32x4*)(&red[1][al][o4]);
  f32x4 s2 = *(const f32x4*)(&red[2][al][o4]);
  f32x4 s3 = *(const f32x4*)(&red[3][al][o4]);
  f32x4 s;
  s[0] = (s0[0] + s1[0]) + (s2[0] + s3[0]);
  s[1] = (s0[1] + s1[1]) + (s2[1] + s3[1]);
  s[2] = (s0[2] + s1[2]) + (s2[2] + s3[2]);
  s[3] = (s0[3] + s1[3]) + (s2[3] + s3[3]);
  *(f32x4*)(part + (size_t)kc * (A_N * D_N) + (size_t)(rt * 16 + al) * D_N + o4) = s;
}

// ---------- final reduce -> f32 out (512 blocks, 1 elem/thread) ----------
__global__ void k_final(const float* __restrict__ part, const float* __restrict__ bond,
                        const float* __restrict__ x, float* __restrict__ out) {
  int i = blockIdx.x * 256 + threadIdx.x;   // 131072 total
  float s = bond[i];
#pragma unroll
  for (int si = 0; si < S_SPLIT; ++si) s += part[(size_t)si * (A_N * D_N) + i];
  out[i] = fmaxf(s + x[i], 0.f);
}

// ---------- launch ----------
extern "C" void kernel_launch(void* const* d_in, const int* in_sizes, int n_in,
                              void* d_out, int out_size, void* d_ws, size_t ws_size,
                              hipStream_t stream) {
  const float* x    = (const float*)d_in[0];
  const float* conn = (const float*)d_in[1];
  const float* bprp = (const float*)d_in[2];
  const float* pf0  = (const float*)d_in[3];
  const float* bf0  = (const float*)d_in[4];
  const float* pf1  = (const float*)d_in[5];
  const float* bf1  = (const float*)d_in[6];
  float* out = (float*)d_out;

  char* ws = (char*)d_ws;
  size_t off = 0;
  short* connb = (short*)(ws + off); off += (size_t)A_N * KTOT * 2;           // 100.7 MB
  short* Bt    = (short*)(ws + off); off += (size_t)D_N * KTOT * 2;           // 3 MB
  float* part  = (float*)(ws + off); off += (size_t)S_SPLIT * A_N * D_N * 4;  // 8.4 MB
  short* xb    = (short*)(ws + off); off += (size_t)A_N * D_N * 2;
  float* bond0 = (float*)(ws + off); off += (size_t)A_N * D_N * 4;
  float* bond1 = (float*)(ws + off); off += (size_t)A_N * D_N * 4;
  short* P2_0  = (short*)(ws + off); off += (size_t)D_N * FL_N * D_N * 2;
  short* P2_1  = (short*)(ws + off); off += (size_t)D_N * FL_N * D_N * 2;

  k_setup_cvt<<<4864, 256, 0, stream>>>(pf0, bf0, pf1, bf1, bprp, x, conn,
                                        P2_0, P2_1, bond0, bond1, xb, connb);

  dim3 ggrid(128, S_SPLIT);

  // conv0: h = x
  k_prep0<<<128, 256, 0, stream>>>(xb, P2_0, Bt);
  k_gemm<0><<<ggrid, 256, 0, stream>>>(connb, Bt, part);

  // conv1: h1 = relu(conv0); bond0; P2_0
  k_prep_r<0><<<128, 256, 0, stream>>>(part, bond0, x, P2_0, Bt);
  k_gemm<1><<<ggrid, 256, 0, stream>>>(connb, Bt, part);

  // conv2: h2 = relu(conv1 + x); bond0 (conv1's); P2_1
  k_prep_r<1><<<128, 256, 0, stream>>>(part, bond0, x, P2_1, Bt);
  k_gemm<2><<<ggrid, 256, 0, stream>>>(connb, Bt, part);

  // conv3: h3 = relu(conv2); bond1 (conv2's); P2_1
  k_prep_r<0><<<128, 256, 0, stream>>>(part, bond1, x, P2_1, Bt);
  k_gemm<3><<<ggrid, 256, 0, stream>>>(connb, Bt, part);

  // out = relu(conv3 + bond1 + x)
  k_final<<<512, 256, 0, stream>>>(part, bond1, x, out);
}

// Round 7
// 182.737 us; speedup vs baseline: 1.8265x; 1.7244x over previous
//
#include <hip/hip_runtime.h>
#include <hip/hip_bf16.h>

#define A_N   2048
#define D_N   64
#define FL_N  12
#define KTOT  (A_N * FL_N)          // 24576
#define S_SPLIT 16
#define KCHUNK 1536                 // cols per kc-chunk (KTOT/16)
#define BKN   128                   // k per staged tile
#define NBK   12                    // KCHUNK/BKN
#define TILE_B 16384                // 64 rows * 128 k * 2B

typedef __attribute__((ext_vector_type(8))) short bf16x8;  // 8 bf16 = 4 VGPRs
typedef __attribute__((ext_vector_type(4))) short bf16x4;  // 8 B
typedef __attribute__((ext_vector_type(4))) float f32x4;

__device__ __forceinline__ short f2bf(float f) {
  union { __hip_bfloat16 b; short s; } u;
  u.b = __float2bfloat16(f);
  return u.s;
}

// ---------- fused setup + conn conversion (tiled layout) ----------
// connb2 layout: tile(rt,kc,bk) = contiguous 16 KB = [row r 0..63][k 0..127] bf16.
// blocks [0,192):   P2_i[o][f][d] = pf_i[o,f,d]*bf_i[o,f,0]
// blocks [192,704): bond_i[a][o]
// blocks [704,768): xb = bf16(x)
// blocks [768,4864): connb2 tiles
__global__ void k_setup_cvt(const float* __restrict__ pf0, const float* __restrict__ bf0,
                            const float* __restrict__ pf1, const float* __restrict__ bf1,
                            const float* __restrict__ bp, const float* __restrict__ x,
                            const float* __restrict__ conn,
                            short* __restrict__ P2_0, short* __restrict__ P2_1,
                            float* __restrict__ bond0, float* __restrict__ bond1,
                            short* __restrict__ xb, short* __restrict__ connb2) {
  int b = blockIdx.x, t = threadIdx.x;
  if (b >= 768) {
    size_t slot = (size_t)(b - 768) * 256 + t;        // < 1048576
#pragma unroll
    for (int cc = 0; cc < 6; ++cc) {
      size_t i = (slot + (size_t)cc * 1048576) * 8;   // covers 50331648 floats exactly
      f32x4 a0 = __builtin_nontemporal_load((const f32x4*)(conn + i));
      f32x4 a1 = __builtin_nontemporal_load((const f32x4*)(conn + i + 4));
      bf16x8 v;
      v[0]=f2bf(a0[0]); v[1]=f2bf(a0[1]); v[2]=f2bf(a0[2]); v[3]=f2bf(a0[3]);
      v[4]=f2bf(a1[0]); v[5]=f2bf(a1[1]); v[6]=f2bf(a1[2]); v[7]=f2bf(a1[3]);
      int a = (int)(i / KTOT), c = (int)(i % KTOT);   // k = c&127 multiple of 8
      int rt = a >> 6, r = a & 63;
      int kc = c / KCHUNK, rem = c % KCHUNK;
      int bk = rem >> 7, k = rem & 127;
      size_t dst = ((size_t)((rt * 16 + kc) * NBK + bk) << 14) + (r << 8) + (k << 1);
      *(bf16x8*)((char*)connb2 + dst) = v;
    }
    return;
  }
  if (b < 192) {
    int idx = b * 256 + t;                       // < 49152
    int f = (idx >> 6) % FL_N;
    int o = idx / (D_N * FL_N);
    P2_0[idx] = f2bf(pf0[idx] * bf0[(o * FL_N + f) * 3]);
    P2_1[idx] = f2bf(pf1[idx] * bf1[(o * FL_N + f) * 3]);
  } else if (b < 704) {
    int o = t & 63;
    int a = (b - 192) * 4 + (t >> 6);
    float s0 = 0.f, s1 = 0.f;
#pragma unroll
    for (int f = 0; f < FL_N; ++f) {
      float c0 = bp[(a * FL_N + f) * 2 + 0];
      float c1 = bp[(a * FL_N + f) * 2 + 1];
      s0 += c0 * bf0[(o * FL_N + f) * 3 + 1] + c1 * bf0[(o * FL_N + f) * 3 + 2];
      s1 += c0 * bf1[(o * FL_N + f) * 3 + 1] + c1 * bf1[(o * FL_N + f) * 3 + 2];
    }
    bond0[a * D_N + o] = s0;
    bond1[a * D_N + o] = s1;
  } else {
    int i = ((b - 704) * 256 + t) * 8;
    f32x4 a0 = *(const f32x4*)(x + i);
    f32x4 a1 = *(const f32x4*)(x + i + 4);
    bf16x8 v;
    v[0]=f2bf(a0[0]); v[1]=f2bf(a0[1]); v[2]=f2bf(a0[2]); v[3]=f2bf(a0[3]);
    v[4]=f2bf(a1[0]); v[5]=f2bf(a1[1]); v[6]=f2bf(a1[2]); v[7]=f2bf(a1[3]);
    *(bf16x8*)(xb + i) = v;
  }
}

// ---------- Bt prep ----------
// Bt2 layout: slab(kc,bk) = contiguous 16 KB = [o 0..63][k 0..127] bf16.
// Bt value at (o, flatcol c=katom*12+f) -> kc=c/1536, bk=(c%1536)>>7, k=c&127.
__device__ __forceinline__ void prep_body(bf16x8 h0, bf16x8 h1,
                                          const short* __restrict__ P2,
                                          short* __restrict__ Bt2,
                                          int k0, int lane, int w) {
  int l15 = lane & 15, grp = lane >> 4;
  const short* prow = P2 + (w * 16 + l15) * (FL_N * D_N) + grp * 8;
  f32x4 acc[FL_N];
#pragma unroll
  for (int f = 0; f < FL_N; ++f) {
    bf16x8 p0 = *(const bf16x8*)(prow + f * D_N);
    bf16x8 p1 = *(const bf16x8*)(prow + f * D_N + 32);
    f32x4 c = {0.f, 0.f, 0.f, 0.f};
    c = __builtin_amdgcn_mfma_f32_16x16x32_bf16(p0, h0, c, 0, 0, 0);
    c = __builtin_amdgcn_mfma_f32_16x16x32_bf16(p1, h1, c, 0, 0, 0);
    acc[f] = c;
  }
  // D layout: row(o) = grp*4 + r (+w*16), col(katom) = l15 (+k0)
#pragma unroll
  for (int r = 0; r < 4; ++r) {
    int o = w * 16 + grp * 4 + r;
    int katom = k0 + l15;
#pragma unroll
    for (int f = 0; f < FL_N; ++f) {
      int c = katom * FL_N + f;
      int kc = c / KCHUNK, rem = c % KCHUNK;
      int bk = rem >> 7, k = rem & 127;
      *(short*)((char*)Bt2 + ((size_t)(kc * NBK + bk) << 14) + (o << 8) + (k << 1))
          = f2bf(acc[f][r]);
    }
  }
}

// prep for conv0: h = xb
__global__ void k_prep0(const short* __restrict__ xb, const short* __restrict__ P2,
                        short* __restrict__ Bt2) {
  int lane = threadIdx.x & 63, w = threadIdx.x >> 6;
  int l15 = lane & 15, grp = lane >> 4;
  int k0 = blockIdx.x * 16;
  const short* hrow = xb + (k0 + l15) * D_N + grp * 8;
  bf16x8 h0 = *(const bf16x8*)(hrow);
  bf16x8 h1 = *(const bf16x8*)(hrow + 32);
  prep_body(h0, h1, P2, Bt2, k0, lane, w);
}

// prep conv c>0: reduce prev partials for 16 atoms, bond(+x)+relu, LDS, MFMA-prep.
template <int ADDX>
__global__ void k_prep_r(const float* __restrict__ part, const float* __restrict__ bond,
                         const float* __restrict__ x, const short* __restrict__ P2,
                         short* __restrict__ Bt2) {
  __shared__ short hsh[16 * 64];
  int t = threadIdx.x;
  int k0 = blockIdx.x * 16;
  int r  = t >> 4;            // 0..15 local row
  int d0 = (t & 15) * 4;      // 4 floats per thread
  size_t base = (size_t)(k0 + r) * D_N + d0;
  f32x4 s = *(const f32x4*)(bond + base);
#pragma unroll
  for (int si = 0; si < S_SPLIT; ++si) {
    f32x4 p = *(const f32x4*)(part + (size_t)si * (A_N * D_N) + base);
    s[0] += p[0]; s[1] += p[1]; s[2] += p[2]; s[3] += p[3];
  }
  if (ADDX) {
    f32x4 xv = *(const f32x4*)(x + base);
    s[0] += xv[0]; s[1] += xv[1]; s[2] += xv[2]; s[3] += xv[3];
  }
  bf16x4 hv;
  hv[0] = f2bf(fmaxf(s[0], 0.f)); hv[1] = f2bf(fmaxf(s[1], 0.f));
  hv[2] = f2bf(fmaxf(s[2], 0.f)); hv[3] = f2bf(fmaxf(s[3], 0.f));
  *(bf16x4*)(&hsh[r * 64 + d0]) = hv;
  __syncthreads();
  int lane = t & 63, w = t >> 6, l15 = lane & 15, grp = lane >> 4;
  bf16x8 h0 = *(const bf16x8*)(&hsh[l15 * 64 + grp * 8]);
  bf16x8 h1 = *(const bf16x8*)(&hsh[l15 * 64 + grp * 8 + 32]);
  prep_body(h0, h1, P2, Bt2, k0, lane, w);
}

// ---------- big GEMM: LDS-staged, reg-staging (T14), XOR-swizzled ----------
// Block (rt,kc): 64 rows x 1536 k; 12 bk-steps of 64x128 A-tile + 64x128 Bt-slab.
// 4 waves split rows (16 each); part[kc][row][o] written wave-direct.
// grid (32,16) = 512 blocks = exactly 2/CU; LDS 64 KB -> 2 blocks/CU.
template <int C>
__global__ __launch_bounds__(256, 2) void k_gemm(const short* __restrict__ connb2,
                                                 const short* __restrict__ Bt2,
                                                 float* __restrict__ part) {
  __shared__ short lA[2][8192];   // 16 KB each buf: [row 64][k 128] swizzled
  __shared__ short lB[2][8192];
  int t = threadIdx.x;
  int lane = t & 63, w = t >> 6, l15 = lane & 15, grp = lane >> 4;
  int rt = blockIdx.x, kc = blockIdx.y;

  const char* Ab = (const char*)connb2 + (((size_t)(rt * 16 + kc) * NBK) << 14);
  const char* Bb = (const char*)Bt2 + (((size_t)kc * NBK) << 14);

  // staging: thread t, round q -> tile chunk j = q*256+t (16 B); LDS XOR-swizzle
  int ldsoff[4];
#pragma unroll
  for (int q = 0; q < 4; ++q) {
    int j = q * 256 + t;
    int row = j >> 4, cw = j & 15;
    ldsoff[q] = (row << 8) + ((cw << 4) ^ ((row & 7) << 4));
  }

  bf16x8 ra[4], rb[4];
#pragma unroll
  for (int q = 0; q < 4; ++q) {
    ra[q] = *(const bf16x8*)(Ab + q * 4096 + t * 16);
    rb[q] = *(const bf16x8*)(Bb + q * 4096 + t * 16);
  }
#pragma unroll
  for (int q = 0; q < 4; ++q) {
    *(bf16x8*)((char*)&lA[0][0] + ldsoff[q]) = ra[q];
    *(bf16x8*)((char*)&lB[0][0] + ldsoff[q]) = rb[q];
  }
  __syncthreads();

  f32x4 acc0 = {0,0,0,0}, acc1 = {0,0,0,0}, acc2 = {0,0,0,0}, acc3 = {0,0,0,0};
  const int arow = (w * 16 + l15) << 8;     // A row byte base
  const int brow = l15 << 8;                // B row byte base (within o-tile)
  const int key  = (l15 & 7) << 4;

#pragma unroll
  for (int bk = 0; bk < NBK; ++bk) {
    const int cur = bk & 1;
    if (bk + 1 < NBK) {                     // issue next-tile loads EARLY (T14)
      const char* An = Ab + (size_t)(bk + 1) * TILE_B;
      const char* Bn = Bb + (size_t)(bk + 1) * TILE_B;
#pragma unroll
      for (int q = 0; q < 4; ++q) {
        ra[q] = *(const bf16x8*)(An + q * 4096 + t * 16);
        rb[q] = *(const bf16x8*)(Bn + q * 4096 + t * 16);
      }
    }
    const char* la = (const char*)&lA[cur][0];
    const char* lb = (const char*)&lB[cur][0];
#pragma unroll
    for (int ks = 0; ks < 4; ++ks) {
      const int cb = ((ks << 6) + (grp << 4)) ^ key;
      bf16x8 af = *(const bf16x8*)(la + arow + cb);
      bf16x8 b0 = *(const bf16x8*)(lb + brow + cb);
      bf16x8 b1 = *(const bf16x8*)(lb + 4096 + brow + cb);
      bf16x8 b2 = *(const bf16x8*)(lb + 8192 + brow + cb);
      bf16x8 b3 = *(const bf16x8*)(lb + 12288 + brow + cb);
      acc0 = __builtin_amdgcn_mfma_f32_16x16x32_bf16(af, b0, acc0, 0, 0, 0);
      acc1 = __builtin_amdgcn_mfma_f32_16x16x32_bf16(af, b1, acc1, 0, 0, 0);
      acc2 = __builtin_amdgcn_mfma_f32_16x16x32_bf16(af, b2, acc2, 0, 0, 0);
      acc3 = __builtin_amdgcn_mfma_f32_16x16x32_bf16(af, b3, acc3, 0, 0, 0);
    }
    if (bk + 1 < NBK) {                     // write-late after compute
      const int nxt = cur ^ 1;
#pragma unroll
      for (int q = 0; q < 4; ++q) {
        *(bf16x8*)((char*)&lA[nxt][0] + ldsoff[q]) = ra[q];
        *(bf16x8*)((char*)&lB[nxt][0] + ldsoff[q]) = rb[q];
      }
    }
    __syncthreads();
  }

  float* p = part + (size_t)kc * (A_N * D_N);
  int rbase = rt * 64 + w * 16 + grp * 4;
#pragma unroll
  for (int r = 0; r < 4; ++r) {
    float* pr = p + (size_t)(rbase + r) * D_N + l15;
    pr[0]  = acc0[r];
    pr[16] = acc1[r];
    pr[32] = acc2[r];
    pr[48] = acc3[r];
  }
}

// ---------- final reduce -> f32 out ----------
__global__ void k_final(const float* __restrict__ part, const float* __restrict__ bond,
                        const float* __restrict__ x, float* __restrict__ out) {
  int i = blockIdx.x * 256 + threadIdx.x;   // 131072 total
  float s = bond[i];
#pragma unroll
  for (int si = 0; si < S_SPLIT; ++si) s += part[(size_t)si * (A_N * D_N) + i];
  out[i] = fmaxf(s + x[i], 0.f);
}

// ---------- launch ----------
extern "C" void kernel_launch(void* const* d_in, const int* in_sizes, int n_in,
                              void* d_out, int out_size, void* d_ws, size_t ws_size,
                              hipStream_t stream) {
  const float* x    = (const float*)d_in[0];
  const float* conn = (const float*)d_in[1];
  const float* bprp = (const float*)d_in[2];
  const float* pf0  = (const float*)d_in[3];
  const float* bf0  = (const float*)d_in[4];
  const float* pf1  = (const float*)d_in[5];
  const float* bf1  = (const float*)d_in[6];
  float* out = (float*)d_out;

  char* ws = (char*)d_ws;
  size_t off = 0;
  short* connb2 = (short*)(ws + off); off += (size_t)A_N * KTOT * 2;           // 100.7 MB
  short* Bt2    = (short*)(ws + off); off += (size_t)D_N * KTOT * 2;           // 3 MB
  float* part   = (float*)(ws + off); off += (size_t)S_SPLIT * A_N * D_N * 4;  // 8.4 MB
  short* xb     = (short*)(ws + off); off += (size_t)A_N * D_N * 2;
  float* bond0  = (float*)(ws + off); off += (size_t)A_N * D_N * 4;
  float* bond1  = (float*)(ws + off); off += (size_t)A_N * D_N * 4;
  short* P2_0   = (short*)(ws + off); off += (size_t)D_N * FL_N * D_N * 2;
  short* P2_1   = (short*)(ws + off); off += (size_t)D_N * FL_N * D_N * 2;

  k_setup_cvt<<<4864, 256, 0, stream>>>(pf0, bf0, pf1, bf1, bprp, x, conn,
                                        P2_0, P2_1, bond0, bond1, xb, connb2);

  dim3 ggrid(32, 16);

  // conv0: h = x
  k_prep0<<<128, 256, 0, stream>>>(xb, P2_0, Bt2);
  k_gemm<0><<<ggrid, 256, 0, stream>>>(connb2, Bt2, part);

  // conv1: h1 = relu(conv0); bond0; P2_0
  k_prep_r<0><<<128, 256, 0, stream>>>(part, bond0, x, P2_0, Bt2);
  k_gemm<1><<<ggrid, 256, 0, stream>>>(connb2, Bt2, part);

  // conv2: h2 = relu(conv1 + x); bond0; P2_1
  k_prep_r<1><<<128, 256, 0, stream>>>(part, bond0, x, P2_1, Bt2);
  k_gemm<2><<<ggrid, 256, 0, stream>>>(connb2, Bt2, part);

  // conv3: h3 = relu(conv2); bond1; P2_1
  k_prep_r<0><<<128, 256, 0, stream>>>(part, bond1, x, P2_1, Bt2);
  k_gemm<3><<<ggrid, 256, 0, stream>>>(connb2, Bt2, part);

  // out = relu(conv3 + bond1 + x)
  k_final<<<512, 256, 0, stream>>>(part, bond1, x, out);
}